// Round 6
// baseline (330.906 us; speedup 1.0000x reference)
//
#include <hip/hip_runtime.h>
#include <hip/hip_cooperative_groups.h>
#include <math.h>

namespace cg = cooperative_groups;

namespace {

constexpr int N  = 4096;
constexpr int E  = 256;
constexpr int H  = 8;
constexpr int DH = 32;
constexpr int BS = 8;
// fold 1/sqrt(DH) and log2(e): softmax in exp2 domain, no max subtraction
// (f32-safe: |s*CL| realistic max ~16, overflow at 127 -> 27 sigma margin)
constexpr float CL = 0.17677669529663687f * 1.4426950408889634f;

typedef __bf16 bf16x8 __attribute__((ext_vector_type(8)));
typedef __bf16 bf16x4 __attribute__((ext_vector_type(4)));
typedef float  f32x4  __attribute__((ext_vector_type(4)));

#if __has_builtin(__builtin_amdgcn_exp2f)
#define EXP2F(x) __builtin_amdgcn_exp2f(x)
#else
#define EXP2F(x) __expf((x) * 0.6931471805599453f)
#endif

__device__ inline bf16x8 pack8(float4 a, float4 b) {
  bf16x8 r;
  r[0] = (__bf16)a.x; r[1] = (__bf16)a.y; r[2] = (__bf16)a.z; r[3] = (__bf16)a.w;
  r[4] = (__bf16)b.x; r[5] = (__bf16)b.y; r[6] = (__bf16)b.z; r[7] = (__bf16)b.w;
  return r;
}

// ---------------------------------------------------------------------------
// Single cooperative kernel: grid 256 x 512 threads (1 block/CU), 4 phases
// separated by grid.sync(). Eliminates 3 dispatch boundaries.
//
// Phase 1 prep : thread tid converts 8 elems of x/pe -> xv, xpe (bf16);
//                tid<32768 converts 8 elems of the 4 weight mats -> wb;
//                tid<=8 computes seg via binary search on sorted xb.
// Phase 2 qkv  : waves 0..1023: Q/K tile-pair (16 rows x 2x64 cols, shared
//                A-frags, 64 MFMA); waves 1024..2047: V tile (16x64) with
//                transposed bf16 store into vt[E][N].
// Phase 3 attn : wave wid -> (rowtile = wid&255, head = wid>>8). Block-diag
//                flash attention, zero per-tile cross-lane ops (permuted
//                key IDs put S^T accumulator regs in P A-frag slots),
//                fixed-base exp2 softmax.
// Phase 4 proj : block = 16 rows; 8 waves = 32-col slices; ctx @ Wo^T + bo
//                + x, then LayerNorm (shuffle + 1KB LDS cross-wave reduce).
// ---------------------------------------------------------------------------
__global__ __launch_bounds__(512) void fused_kernel(
    const float* __restrict__ x, const float* __restrict__ pe,
    const int* __restrict__ xb,
    const float* __restrict__ Wq, const float* __restrict__ Wk,
    const float* __restrict__ Wv, const float* __restrict__ Wo,
    const float* __restrict__ bq, const float* __restrict__ bk,
    const float* __restrict__ bv, const float* __restrict__ bo,
    const float* __restrict__ gamma, const float* __restrict__ beta,
    float* __restrict__ out,
    __bf16* __restrict__ qb, __bf16* __restrict__ kb,
    __bf16* __restrict__ vt, __bf16* __restrict__ ctxb,
    __bf16* __restrict__ xpe, __bf16* __restrict__ xv,
    __bf16* __restrict__ wb, int* __restrict__ seg)
{
  cg::grid_group grid = cg::this_grid();
  const int tid  = blockIdx.x * 512 + threadIdx.x;
  const int wid  = tid >> 6;          // global wave id, [0, 2048)
  const int lane = threadIdx.x & 63;
  const int l15  = lane & 15;
  const int g    = lane >> 4;         // [0,4)

  // ======== phase 1: prep ========
  {
    const size_t e0 = (size_t)tid * 8;
    float4 a0 = *(const float4*)(x + e0);
    float4 a1 = *(const float4*)(x + e0 + 4);
    const float4 p0 = *(const float4*)(pe + e0);
    const float4 p1 = *(const float4*)(pe + e0 + 4);
    *reinterpret_cast<bf16x8*>(xv + e0) = pack8(a0, a1);
    a0.x += p0.x; a0.y += p0.y; a0.z += p0.z; a0.w += p0.w;
    a1.x += p1.x; a1.y += p1.y; a1.z += p1.z; a1.w += p1.w;
    *reinterpret_cast<bf16x8*>(xpe + e0) = pack8(a0, a1);

    if (tid < 32768) {
      const size_t w0 = (size_t)tid * 8;
      const int mat = (int)(w0 >> 16);
      const size_t off = w0 & 65535;
      const float* __restrict__ W =
          (mat == 0) ? Wq : (mat == 1) ? Wk : (mat == 2) ? Wv : Wo;
      *reinterpret_cast<bf16x8*>(wb + w0) =
          pack8(*(const float4*)(W + off), *(const float4*)(W + off + 4));
    }
    if (tid <= BS) {
      int lo = 0, hi = N;
      while (lo < hi) { int mid = (lo + hi) >> 1; if (xb[mid] < tid) lo = mid + 1; else hi = mid; }
      seg[tid] = lo;
    }
  }
  __threadfence();
  grid.sync();

  // ======== phase 2: QKV projections ========
  if (wid < 1024) {
    // Q/K pair: tiles t=2*wid, 2*wid+1 -> same mat, same 16 rows, col
    // slices wn0 and wn0+1 (64 cols each). A-fragments shared.
    const int t   = 2 * wid;
    const int mat = t >> 10;            // 0=Q, 1=K
    const int rem = t & 1023;
    const int m0  = (rem >> 2) * 16;
    const int wn0 = rem & 3;            // even
    const int mrow = m0 + l15;
    const __bf16* __restrict__ W = wb + (size_t)mat * E * E;

    bf16x8 af[8];
#pragma unroll
    for (int kk = 0; kk < 8; ++kk)
      af[kk] = *reinterpret_cast<const bf16x8*>(xpe + (size_t)mrow * E + kk * 32 + 8 * g);

    f32x4 acc[2][4];
#pragma unroll
    for (int sl = 0; sl < 2; ++sl)
#pragma unroll
      for (int nt = 0; nt < 4; ++nt) acc[sl][nt] = f32x4{0.f, 0.f, 0.f, 0.f};

#pragma unroll
    for (int kk = 0; kk < 8; ++kk)
#pragma unroll
      for (int sl = 0; sl < 2; ++sl)
#pragma unroll
        for (int nt = 0; nt < 4; ++nt) {
          const bf16x8 wf = *reinterpret_cast<const bf16x8*>(
              W + (size_t)((wn0 + sl) * 64 + nt * 16 + l15) * E + kk * 32 + 8 * g);
          acc[sl][nt] = __builtin_amdgcn_mfma_f32_16x16x32_bf16(wf, af[kk],
                                                                acc[sl][nt], 0, 0, 0);
        }

    __bf16* __restrict__ outb = mat ? kb : qb;
    const float* __restrict__ bi = mat ? bk : bq;
#pragma unroll
    for (int sl = 0; sl < 2; ++sl)
#pragma unroll
      for (int nt = 0; nt < 4; ++nt) {
        const int n_base = (wn0 + sl) * 64 + nt * 16 + 4 * g;
        const float4 bb = *(const float4*)(bi + n_base);
        bf16x4 o;
        o.x = (__bf16)(acc[sl][nt][0] + bb.x);
        o.y = (__bf16)(acc[sl][nt][1] + bb.y);
        o.z = (__bf16)(acc[sl][nt][2] + bb.z);
        o.w = (__bf16)(acc[sl][nt][3] + bb.w);
        *reinterpret_cast<bf16x4*>(outb + (size_t)mrow * E + n_base) = o;
      }
  } else {
    // V tile: 16 rows x 64 cols, transposed store into vt[E][N]
    const int rem = wid - 1024;         // [0,1024)
    const int m0  = (rem >> 2) * 16;
    const int wn  = rem & 3;
    const int mrow = m0 + l15;
    const __bf16* __restrict__ W = wb + 2 * (size_t)E * E;

    bf16x8 af[8];
#pragma unroll
    for (int kk = 0; kk < 8; ++kk)
      af[kk] = *reinterpret_cast<const bf16x8*>(xv + (size_t)mrow * E + kk * 32 + 8 * g);

    f32x4 acc[4];
#pragma unroll
    for (int nt = 0; nt < 4; ++nt) acc[nt] = f32x4{0.f, 0.f, 0.f, 0.f};

#pragma unroll
    for (int kk = 0; kk < 8; ++kk)
#pragma unroll
      for (int nt = 0; nt < 4; ++nt) {
        const bf16x8 wf = *reinterpret_cast<const bf16x8*>(
            W + (size_t)(wn * 64 + nt * 16 + l15) * E + kk * 32 + 8 * g);
        acc[nt] = __builtin_amdgcn_mfma_f32_16x16x32_bf16(wf, af[kk], acc[nt], 0, 0, 0);
      }

#pragma unroll
    for (int nt = 0; nt < 4; ++nt) {
      const int n_base = wn * 64 + nt * 16 + 4 * g;
      const float4 bb = *(const float4*)(bv + n_base);
      const float bbr[4] = {bb.x, bb.y, bb.z, bb.w};
#pragma unroll
      for (int r = 0; r < 4; ++r)
        vt[(size_t)(n_base + r) * N + mrow] = (__bf16)(acc[nt][r] + bbr[r]);
    }
  }
  __threadfence();
  grid.sync();

  // ======== phase 3: attention ========
  {
    const int h       = wid >> 8;           // [0,8)
    const int rowbase = (wid & 255) * 16;
    const int hd   = h * DH;
    const int qrow = rowbase + l15;

    const int b  = xb[qrow];
    const int lo = seg[b];
    const int hi = seg[b + 1];

    const bf16x8 qf = *reinterpret_cast<const bf16x8*>(
        qb + (size_t)qrow * E + hd + g * 8);

    const int kstart = __shfl(lo, 0, 64);
    const int kend   = __shfl(hi, 15, 64);

    const int base_l = ((l15 & 12) << 1) + (l15 & 3);  // 8*(l15>>2) + (l15&3)

    f32x4 acc0 = {0.f, 0.f, 0.f, 0.f};
    f32x4 acc1 = {0.f, 0.f, 0.f, 0.f};
    float lsum = 0.f;

    for (int j0 = kstart & ~63; j0 < kend; j0 += 64) {
      bf16x8 kf[4];
#pragma unroll
      for (int mt = 0; mt < 4; ++mt) {
        const int krow = j0 + base_l + 32 * (mt >> 1) + 4 * (mt & 1);
        kf[mt] = *reinterpret_cast<const bf16x8*>(kb + (size_t)krow * E + hd + g * 8);
      }
      bf16x8 vf[2][2];
#pragma unroll
      for (int ks = 0; ks < 2; ++ks)
#pragma unroll
        for (int dh = 0; dh < 2; ++dh)
          vf[ks][dh] = *reinterpret_cast<const bf16x8*>(
              vt + (size_t)(hd + 16 * dh + l15) * N + j0 + 32 * ks + 8 * g);

      f32x4 s[4];
#pragma unroll
      for (int mt = 0; mt < 4; ++mt) {
        const f32x4 z = {0.f, 0.f, 0.f, 0.f};
        s[mt] = __builtin_amdgcn_mfma_f32_16x16x32_bf16(kf[mt], qf, z, 0, 0, 0);
      }

      bf16x8 pa[2];
#pragma unroll
      for (int ks = 0; ks < 2; ++ks)
#pragma unroll
        for (int b_ = 0; b_ < 2; ++b_)
#pragma unroll
          for (int r = 0; r < 4; ++r) {
            const int key = j0 + 32 * ks + 8 * g + 4 * b_ + r;
            const float sc = s[2 * ks + b_][r] * CL;
            const float e  = (key >= lo && key < hi) ? EXP2F(sc) : 0.f;
            lsum += e;
            pa[ks][4 * b_ + r] = (__bf16)e;
          }

#pragma unroll
      for (int ks = 0; ks < 2; ++ks) {
        acc0 = __builtin_amdgcn_mfma_f32_16x16x32_bf16(pa[ks], vf[ks][0], acc0, 0, 0, 0);
        acc1 = __builtin_amdgcn_mfma_f32_16x16x32_bf16(pa[ks], vf[ks][1], acc1, 0, 0, 0);
      }
    }

    lsum += __shfl_xor(lsum, 16, 64);
    lsum += __shfl_xor(lsum, 32, 64);
    const float inv = 1.0f / lsum;
    float invr[4];
#pragma unroll
    for (int r = 0; r < 4; ++r) invr[r] = __shfl(inv, 4 * g + r, 64);

    __bf16* __restrict__ cb = ctxb + (size_t)rowbase * E + hd + l15;
#pragma unroll
    for (int r = 0; r < 4; ++r) {
      cb[(size_t)(4 * g + r) * E]      = (__bf16)(acc0[r] * invr[r]);
      cb[(size_t)(4 * g + r) * E + 16] = (__bf16)(acc1[r] * invr[r]);
    }
  }
  __threadfence();
  grid.sync();

  // ======== phase 4: output projection + residual + LayerNorm ========
  {
    const int m0 = blockIdx.x * 16;
    const int wn = threadIdx.x >> 6;    // [0,8): 32-col slice
    const __bf16* __restrict__ wo = wb + 3 * (size_t)E * E;

    bf16x8 af[8];
#pragma unroll
    for (int kk = 0; kk < 8; ++kk)
      af[kk] = *reinterpret_cast<const bf16x8*>(
          ctxb + (size_t)(m0 + l15) * E + kk * 32 + 8 * g);

    f32x4 acc[2];
    acc[0] = f32x4{0.f, 0.f, 0.f, 0.f};
    acc[1] = f32x4{0.f, 0.f, 0.f, 0.f};

#pragma unroll
    for (int kk = 0; kk < 8; ++kk)
#pragma unroll
      for (int nt = 0; nt < 2; ++nt) {
        const bf16x8 wf = *reinterpret_cast<const bf16x8*>(
            wo + (size_t)(wn * 32 + nt * 16 + l15) * E + kk * 32 + 8 * g);
        acc[nt] = __builtin_amdgcn_mfma_f32_16x16x32_bf16(af[kk], wf, acc[nt], 0, 0, 0);
      }

    float yv[2][4];
    float s1[4], s2[4];
#pragma unroll
    for (int r = 0; r < 4; ++r) { s1[r] = 0.f; s2[r] = 0.f; }
#pragma unroll
    for (int nt = 0; nt < 2; ++nt) {
      const int c = wn * 32 + nt * 16 + l15;
      const float bb = bo[c];
#pragma unroll
      for (int r = 0; r < 4; ++r) {
        const int row = m0 + 4 * g + r;
        const float y = acc[nt][r] + bb + x[(size_t)row * E + c];
        yv[nt][r] = y;
        s1[r] += y;
        s2[r] += y * y;
      }
    }
#pragma unroll
    for (int off = 1; off < 16; off <<= 1) {
#pragma unroll
      for (int r = 0; r < 4; ++r) {
        s1[r] += __shfl_xor(s1[r], off, 64);
        s2[r] += __shfl_xor(s2[r], off, 64);
      }
    }
    __shared__ float redS[8][16];
    __shared__ float redQ[8][16];
    if (l15 == 0) {
#pragma unroll
      for (int r = 0; r < 4; ++r) {
        redS[wn][4 * g + r] = s1[r];
        redQ[wn][4 * g + r] = s2[r];
      }
    }
    __syncthreads();
    float mu[4], rs[4];
#pragma unroll
    for (int r = 0; r < 4; ++r) {
      float ts = 0.f, tq = 0.f;
#pragma unroll
      for (int w = 0; w < 8; ++w) { ts += redS[w][4 * g + r]; tq += redQ[w][4 * g + r]; }
      mu[r] = ts * (1.0f / E);
      const float var = tq * (1.0f / E) - mu[r] * mu[r];
      rs[r] = rsqrtf(var + 1e-5f);
    }
#pragma unroll
    for (int nt = 0; nt < 2; ++nt) {
      const int c = wn * 32 + nt * 16 + l15;
      const float gg = gamma[c];
      const float bt = beta[c];
#pragma unroll
      for (int r = 0; r < 4; ++r) {
        const int row = m0 + 4 * g + r;
        out[(size_t)row * E + c] = (yv[nt][r] - mu[r]) * rs[r] * gg + bt;
      }
    }
  }
}

}  // namespace

extern "C" void kernel_launch(void* const* d_in, const int* in_sizes, int n_in,
                              void* d_out, int out_size, void* d_ws, size_t ws_size,
                              hipStream_t stream) {
  const float* x     = (const float*)d_in[0];
  const float* pe    = (const float*)d_in[1];
  const int*   xb    = (const int*)d_in[2];
  const float* Wq    = (const float*)d_in[3];
  const float* Wk    = (const float*)d_in[4];
  const float* Wv    = (const float*)d_in[5];
  const float* bq    = (const float*)d_in[6];
  const float* bk    = (const float*)d_in[7];
  const float* bv    = (const float*)d_in[8];
  const float* Wo    = (const float*)d_in[9];
  const float* bo    = (const float*)d_in[10];
  const float* gamma = (const float*)d_in[11];
  const float* beta  = (const float*)d_in[12];
  float* out = (float*)d_out;

  char* wsb = (char*)d_ws;
  const size_t NE = (size_t)N * E;          // 1,048,576 elements
  __bf16* qb16  = (__bf16*)(wsb);                   // 2 MB
  __bf16* kb16  = (__bf16*)(wsb + 2 * NE);          // 2 MB
  __bf16* vt16  = (__bf16*)(wsb + 4 * NE);          // 2 MB  [E][N]
  __bf16* ctx16 = (__bf16*)(wsb + 6 * NE);          // 2 MB
  __bf16* xpe16 = (__bf16*)(wsb + 8 * NE);          // 2 MB
  __bf16* xv16  = (__bf16*)(wsb + 10 * NE);         // 2 MB
  __bf16* wb16  = (__bf16*)(wsb + 12 * NE);         // 512 KB (4 mats)
  int*    seg   = (int*)(wsb + 12 * NE + 4 * (size_t)E * E * 2);

  void* args[] = {
      (void*)&x,  (void*)&pe, (void*)&xb,
      (void*)&Wq, (void*)&Wk, (void*)&Wv, (void*)&Wo,
      (void*)&bq, (void*)&bk, (void*)&bv, (void*)&bo,
      (void*)&gamma, (void*)&beta, (void*)&out,
      (void*)&qb16, (void*)&kb16, (void*)&vt16, (void*)&ctx16,
      (void*)&xpe16, (void*)&xv16, (void*)&wb16, (void*)&seg};
  hipLaunchCooperativeKernel(reinterpret_cast<const void*>(&fused_kernel),
                             dim3(256), dim3(512), args, 0, stream);
}

// Round 7
// 70.154 us; speedup vs baseline: 4.7168x; 4.7168x over previous
//
#include <hip/hip_runtime.h>
#include <math.h>

namespace {

constexpr int N  = 4096;
constexpr int E  = 256;
constexpr int H  = 8;
constexpr int DH = 32;
constexpr int BS = 8;
// fold 1/sqrt(DH) and log2(e): softmax in exp2 domain, no max subtraction
// (f32-safe: |s*CL| realistic max ~16, overflow at 127 -> 27 sigma margin)
constexpr float CL = 0.17677669529663687f * 1.4426950408889634f;

typedef __bf16 bf16x8 __attribute__((ext_vector_type(8)));
typedef __bf16 bf16x4 __attribute__((ext_vector_type(4)));
typedef float  f32x4  __attribute__((ext_vector_type(4)));

#if __has_builtin(__builtin_amdgcn_exp2f)
#define EXP2F(x) __builtin_amdgcn_exp2f(x)
#else
#define EXP2F(x) __expf((x) * 0.6931471805599453f)
#endif

__device__ inline bf16x8 pack8(float4 a, float4 b) {
  bf16x8 r;
  r[0] = (__bf16)a.x; r[1] = (__bf16)a.y; r[2] = (__bf16)a.z; r[3] = (__bf16)a.w;
  r[4] = (__bf16)b.x; r[5] = (__bf16)b.y; r[6] = (__bf16)b.z; r[7] = (__bf16)b.w;
  return r;
}

// ---------------------------------------------------------------------------
// prep: one memory-bound pass producing all bf16 operands.
//  blocks [0,512):   xpe = bf16(x+pe), xv = bf16(x)   (8 elems/thread)
//  blocks [512,640): wb[mat][n][k] = bf16(W)  mat: 0=Wq 1=Wk 2=Wv 3=Wo
//  block 640:        seg[t] via binary search on sorted xb
// ---------------------------------------------------------------------------
__global__ __launch_bounds__(256) void prep_kernel(
    const float* __restrict__ x, const float* __restrict__ pe,
    const int* __restrict__ xb,
    const float* __restrict__ Wq, const float* __restrict__ Wk,
    const float* __restrict__ Wv, const float* __restrict__ Wo,
    __bf16* __restrict__ xpe, __bf16* __restrict__ xv,
    __bf16* __restrict__ wb, int* __restrict__ seg)
{
  const int bid = blockIdx.x;
  if (bid < 512) {
    const size_t e0 = ((size_t)bid * 256 + threadIdx.x) * 8;
    float4 a0 = *(const float4*)(x + e0);
    float4 a1 = *(const float4*)(x + e0 + 4);
    const float4 p0 = *(const float4*)(pe + e0);
    const float4 p1 = *(const float4*)(pe + e0 + 4);
    *reinterpret_cast<bf16x8*>(xv + e0) = pack8(a0, a1);
    a0.x += p0.x; a0.y += p0.y; a0.z += p0.z; a0.w += p0.w;
    a1.x += p1.x; a1.y += p1.y; a1.z += p1.z; a1.w += p1.w;
    *reinterpret_cast<bf16x8*>(xpe + e0) = pack8(a0, a1);
  } else if (bid < 640) {
    const size_t e0 = ((size_t)(bid - 512) * 256 + threadIdx.x) * 8;
    const int mat = (int)(e0 >> 16);
    const size_t off = e0 & 65535;
    const float* __restrict__ W =
        (mat == 0) ? Wq : (mat == 1) ? Wk : (mat == 2) ? Wv : Wo;
    *reinterpret_cast<bf16x8*>(wb + e0) =
        pack8(*(const float4*)(W + off), *(const float4*)(W + off + 4));
  } else {
    if (threadIdx.x <= BS) {
      const int t = threadIdx.x;
      int lo = 0, hi = N;
      while (lo < hi) { int mid = (lo + hi) >> 1; if (xb[mid] < t) lo = mid + 1; else hi = mid; }
      seg[t] = lo;
    }
  }
}

// ---------------------------------------------------------------------------
// MFMA QKV, pure bf16 operands: out = A @ W^T + b.
// Block = 16 rows x 128 cols (half of E), 4 waves (wave = 32-col slice).
// Grid (512, 3) = 1536 blocks -> 6 blocks/CU, 24 waves/CU (2x round 5's
// occupancy; round-4 counters showed qkv was a latency queue at 22%).
// Q,K stored bf16 [N][E]; V stored transposed vt[E][N].
// ---------------------------------------------------------------------------
__global__ __launch_bounds__(256) void qkv_mfma(
    const __bf16* __restrict__ xpe, const __bf16* __restrict__ xv,
    const __bf16* __restrict__ wb,
    const float* __restrict__ bq, const float* __restrict__ bk,
    const float* __restrict__ bv,
    __bf16* __restrict__ qo, __bf16* __restrict__ ko,
    __bf16* __restrict__ vt)
{
  const int mat  = blockIdx.y;
  const int m0   = (blockIdx.x >> 1) * 16;
  const int half = blockIdx.x & 1;
  const int wv   = threadIdx.x >> 6;
  const int lane = threadIdx.x & 63;
  const int l15  = lane & 15, g = lane >> 4;
  const int cb0  = half * 128 + wv * 32;

  const __bf16* __restrict__ A = (mat < 2) ? xpe : xv;
  const __bf16* __restrict__ W = wb + (size_t)mat * E * E;
  const int mrow = m0 + l15;

  bf16x8 af[8];
#pragma unroll
  for (int kk = 0; kk < 8; ++kk)
    af[kk] = *reinterpret_cast<const bf16x8*>(A + (size_t)mrow * E + kk * 32 + 8 * g);

  f32x4 acc[2];
  acc[0] = f32x4{0.f, 0.f, 0.f, 0.f};
  acc[1] = f32x4{0.f, 0.f, 0.f, 0.f};

#pragma unroll
  for (int kk = 0; kk < 8; ++kk)
#pragma unroll
    for (int nt = 0; nt < 2; ++nt) {
      const bf16x8 wf = *reinterpret_cast<const bf16x8*>(
          W + (size_t)(cb0 + nt * 16 + l15) * E + kk * 32 + 8 * g);
      acc[nt] = __builtin_amdgcn_mfma_f32_16x16x32_bf16(wf, af[kk], acc[nt], 0, 0, 0);
    }

  if (mat < 2) {
    __bf16* __restrict__ outb = mat ? ko : qo;
    const float* __restrict__ bi = mat ? bk : bq;
#pragma unroll
    for (int nt = 0; nt < 2; ++nt) {
      const int n_base = cb0 + nt * 16 + 4 * g;
      const float4 bb = *(const float4*)(bi + n_base);
      bf16x4 o;
      o.x = (__bf16)(acc[nt][0] + bb.x);
      o.y = (__bf16)(acc[nt][1] + bb.y);
      o.z = (__bf16)(acc[nt][2] + bb.z);
      o.w = (__bf16)(acc[nt][3] + bb.w);
      *reinterpret_cast<bf16x4*>(outb + (size_t)mrow * E + n_base) = o;
    }
  } else {
#pragma unroll
    for (int nt = 0; nt < 2; ++nt) {
      const int n_base = cb0 + nt * 16 + 4 * g;
      const float4 bb = *(const float4*)(bv + n_base);
      const float bbr[4] = {bb.x, bb.y, bb.z, bb.w};
#pragma unroll
      for (int r = 0; r < 4; ++r)
        vt[(size_t)(n_base + r) * N + mrow] = (__bf16)(acc[nt][r] + bbr[r]);
    }
  }
}

// ---------------------------------------------------------------------------
// Fused attention + output projection + residual + LayerNorm.
// Block = 16 query rows, 512 threads = 8 waves, wave = head.
//  Phase A (attn, proven round-5 wave body): block-diag flash attention,
//    zero per-tile cross-lane ops (permuted key IDs put the S^T accumulator
//    regs directly into the P A-fragment slots), fixed-base exp2 softmax.
//    Each wave parks its 16x32 bf16 ctx tile in LDS (stride 264: uniform
//    bank spread for the phase-B ds_read_b128).
//  Phase B: proj from LDS A-frags + Wo(bf16), + bo + x residual, LayerNorm
//    via xor-shuffle + 1KB cross-wave LDS reduce. Saves one dispatch and the
//    4MB global ctx round-trip vs round 5.
// ---------------------------------------------------------------------------
__global__ __launch_bounds__(512) void attn_proj_ln(
    const __bf16* __restrict__ qb, const __bf16* __restrict__ kb,
    const __bf16* __restrict__ vt, const int* __restrict__ xb,
    const int* __restrict__ seg,
    const float* __restrict__ x, const __bf16* __restrict__ wo,
    const float* __restrict__ bo, const float* __restrict__ gamma,
    const float* __restrict__ beta, float* __restrict__ out)
{
  const int m0   = blockIdx.x * 16;
  const int h    = threadIdx.x >> 6;    // wave = head
  const int lane = threadIdx.x & 63;
  const int l15  = lane & 15;
  const int g    = lane >> 4;
  const int hd   = h * DH;
  const int qrow = m0 + l15;

  __shared__ __bf16 cl[16][264];        // ctx tile, padded stride
  __shared__ float redS[8][16];
  __shared__ float redQ[8][16];

  // ======== phase A: attention ========
  {
    const int b  = xb[qrow];
    const int lo = seg[b];
    const int hi = seg[b + 1];

    const bf16x8 qf = *reinterpret_cast<const bf16x8*>(
        qb + (size_t)qrow * E + hd + g * 8);

    const int kstart = __shfl(lo, 0, 64);
    const int kend   = __shfl(hi, 15, 64);

    const int base_l = ((l15 & 12) << 1) + (l15 & 3);  // 8*(l15>>2) + (l15&3)

    f32x4 acc0 = {0.f, 0.f, 0.f, 0.f};
    f32x4 acc1 = {0.f, 0.f, 0.f, 0.f};
    float lsum = 0.f;

    for (int j0 = kstart & ~63; j0 < kend; j0 += 64) {
      bf16x8 kf[4];
#pragma unroll
      for (int mt = 0; mt < 4; ++mt) {
        const int krow = j0 + base_l + 32 * (mt >> 1) + 4 * (mt & 1);
        kf[mt] = *reinterpret_cast<const bf16x8*>(kb + (size_t)krow * E + hd + g * 8);
      }
      bf16x8 vf[2][2];
#pragma unroll
      for (int ks = 0; ks < 2; ++ks)
#pragma unroll
        for (int dh = 0; dh < 2; ++dh)
          vf[ks][dh] = *reinterpret_cast<const bf16x8*>(
              vt + (size_t)(hd + 16 * dh + l15) * N + j0 + 32 * ks + 8 * g);

      f32x4 s[4];
#pragma unroll
      for (int mt = 0; mt < 4; ++mt) {
        const f32x4 z = {0.f, 0.f, 0.f, 0.f};
        s[mt] = __builtin_amdgcn_mfma_f32_16x16x32_bf16(kf[mt], qf, z, 0, 0, 0);
      }

      bf16x8 pa[2];
#pragma unroll
      for (int ks = 0; ks < 2; ++ks)
#pragma unroll
        for (int b_ = 0; b_ < 2; ++b_)
#pragma unroll
          for (int r = 0; r < 4; ++r) {
            const int key = j0 + 32 * ks + 8 * g + 4 * b_ + r;
            const float sc = s[2 * ks + b_][r] * CL;
            const float e  = (key >= lo && key < hi) ? EXP2F(sc) : 0.f;
            lsum += e;
            pa[ks][4 * b_ + r] = (__bf16)e;
          }

#pragma unroll
      for (int ks = 0; ks < 2; ++ks) {
        acc0 = __builtin_amdgcn_mfma_f32_16x16x32_bf16(pa[ks], vf[ks][0], acc0, 0, 0, 0);
        acc1 = __builtin_amdgcn_mfma_f32_16x16x32_bf16(pa[ks], vf[ks][1], acc1, 0, 0, 0);
      }
    }

    lsum += __shfl_xor(lsum, 16, 64);
    lsum += __shfl_xor(lsum, 32, 64);
    const float inv = 1.0f / lsum;
    float invr[4];
#pragma unroll
    for (int r = 0; r < 4; ++r) invr[r] = __shfl(inv, 4 * g + r, 64);

#pragma unroll
    for (int r = 0; r < 4; ++r) {
      cl[4 * g + r][hd + l15]      = (__bf16)(acc0[r] * invr[r]);
      cl[4 * g + r][hd + 16 + l15] = (__bf16)(acc1[r] * invr[r]);
    }
  }
  __syncthreads();

  // ======== phase B: projection + residual + LayerNorm ========
  {
    bf16x8 af[8];
#pragma unroll
    for (int kk = 0; kk < 8; ++kk)
      af[kk] = *reinterpret_cast<const bf16x8*>(&cl[l15][kk * 32 + 8 * g]);

    f32x4 acc[2];
    acc[0] = f32x4{0.f, 0.f, 0.f, 0.f};
    acc[1] = f32x4{0.f, 0.f, 0.f, 0.f};

#pragma unroll
    for (int kk = 0; kk < 8; ++kk)
#pragma unroll
      for (int nt = 0; nt < 2; ++nt) {
        const bf16x8 wf = *reinterpret_cast<const bf16x8*>(
            wo + (size_t)(h * 32 + nt * 16 + l15) * E + kk * 32 + 8 * g);
        acc[nt] = __builtin_amdgcn_mfma_f32_16x16x32_bf16(af[kk], wf, acc[nt], 0, 0, 0);
      }

    float yv[2][4];
    float s1[4], s2[4];
#pragma unroll
    for (int r = 0; r < 4; ++r) { s1[r] = 0.f; s2[r] = 0.f; }
#pragma unroll
    for (int nt = 0; nt < 2; ++nt) {
      const int c = h * 32 + nt * 16 + l15;
      const float bb = bo[c];
#pragma unroll
      for (int r = 0; r < 4; ++r) {
        const int row = m0 + 4 * g + r;
        const float y = acc[nt][r] + bb + x[(size_t)row * E + c];
        yv[nt][r] = y;
        s1[r] += y;
        s2[r] += y * y;
      }
    }
#pragma unroll
    for (int off = 1; off < 16; off <<= 1) {
#pragma unroll
      for (int r = 0; r < 4; ++r) {
        s1[r] += __shfl_xor(s1[r], off, 64);
        s2[r] += __shfl_xor(s2[r], off, 64);
      }
    }
    if (l15 == 0) {
#pragma unroll
      for (int r = 0; r < 4; ++r) {
        redS[h][4 * g + r] = s1[r];
        redQ[h][4 * g + r] = s2[r];
      }
    }
    __syncthreads();
    float mu[4], rs[4];
#pragma unroll
    for (int r = 0; r < 4; ++r) {
      float ts = 0.f, tq = 0.f;
#pragma unroll
      for (int w = 0; w < 8; ++w) { ts += redS[w][4 * g + r]; tq += redQ[w][4 * g + r]; }
      mu[r] = ts * (1.0f / E);
      const float var = tq * (1.0f / E) - mu[r] * mu[r];
      rs[r] = rsqrtf(var + 1e-5f);
    }
#pragma unroll
    for (int nt = 0; nt < 2; ++nt) {
      const int c = h * 32 + nt * 16 + l15;
      const float gg = gamma[c];
      const float bt = beta[c];
#pragma unroll
      for (int r = 0; r < 4; ++r) {
        const int row = m0 + 4 * g + r;
        out[(size_t)row * E + c] = (yv[nt][r] - mu[r]) * rs[r] * gg + bt;
      }
    }
  }
}

}  // namespace

extern "C" void kernel_launch(void* const* d_in, const int* in_sizes, int n_in,
                              void* d_out, int out_size, void* d_ws, size_t ws_size,
                              hipStream_t stream) {
  const float* x     = (const float*)d_in[0];
  const float* pe    = (const float*)d_in[1];
  const int*   xb    = (const int*)d_in[2];
  const float* Wq    = (const float*)d_in[3];
  const float* Wk    = (const float*)d_in[4];
  const float* Wv    = (const float*)d_in[5];
  const float* bq    = (const float*)d_in[6];
  const float* bk    = (const float*)d_in[7];
  const float* bv    = (const float*)d_in[8];
  const float* Wo    = (const float*)d_in[9];
  const float* bo    = (const float*)d_in[10];
  const float* gamma = (const float*)d_in[11];
  const float* beta  = (const float*)d_in[12];
  float* out = (float*)d_out;

  char* wsb = (char*)d_ws;
  const size_t NE = (size_t)N * E;          // 1,048,576 elements
  __bf16* qb16  = (__bf16*)(wsb);                   // 2 MB
  __bf16* kb16  = (__bf16*)(wsb + 2 * NE);          // 2 MB
  __bf16* vt16  = (__bf16*)(wsb + 4 * NE);          // 2 MB  [E][N]
  __bf16* xpe16 = (__bf16*)(wsb + 6 * NE);          // 2 MB
  __bf16* xv16  = (__bf16*)(wsb + 8 * NE);          // 2 MB
  __bf16* wb16  = (__bf16*)(wsb + 10 * NE);         // 512 KB (4 mats)
  int*    seg   = (int*)(wsb + 10 * NE + 4 * (size_t)E * E * 2);

  prep_kernel<<<dim3(641), 256, 0, stream>>>(x, pe, xb, Wq, Wk, Wv, Wo,
                                             xpe16, xv16, wb16, seg);
  qkv_mfma<<<dim3(512, 3), 256, 0, stream>>>(xpe16, xv16, wb16, bq, bk, bv,
                                             qb16, kb16, vt16);
  attn_proj_ln<<<dim3(256), 512, 0, stream>>>(qb16, kb16, vt16, xb, seg,
                                              x, wb16 + 3 * (size_t)E * E,
                                              bo, gamma, beta, out);
}